// Round 1
// baseline (569.001 us; speedup 1.0000x reference)
//
#include <hip/hip_runtime.h>
#include <hip/hip_bf16.h>
#include <math.h>

typedef unsigned int u32;
typedef unsigned long long u64;

#define NCLS 80
#define KLVL 1000
#define CAP  8192
#define TARGET 1100u

// workspace byte offsets (all 16B aligned)
#define OFF_CAND   0u        // u64 [3][8192]
#define OFF_HIST   196608u   // u32 [3][2048]
#define OFF_CNT    221184u   // u32 [8]: [0..2]=cand counts, [4..6]=threshold bits
#define OFF_GFLAT  221216u   // u32 [3000]
#define OFF_GSB    233216u   // u32 [3000]
#define OFF_SRT    245216u   // u32 [3000]
#define OFF_QX1    257216u   // f32 [3000]
#define OFF_QY1    269216u
#define OFF_QX2    281216u
#define OFF_QY2    293216u
#define OFF_AREA   305216u
#define OFF_SCORE  317216u
#define OFF_LABEL  329216u   // u32
#define OFF_VALID  341216u   // u32
#define OFF_KEEP   353216u   // u32
#define OFF_OBOX   365216u   // f32 [3000][4]
#define OFF_SOBJ   413216u   // f32 [100800] cheap sigmoid(obj)

__constant__ float cANCH[3][3][2] = {
  {{10.f,13.f},{16.f,30.f},{33.f,23.f}},
  {{30.f,61.f},{62.f,45.f},{59.f,119.f}},
  {{116.f,90.f},{156.f,198.f},{373.f,326.f}}
};

// ---- sigmoid helpers ----
// cheap: used only for histogram binning / candidate prefilter (64-ulp slack covers its error)
__device__ __forceinline__ float sig_fast(float x) {
  return 1.0f / (1.0f + __expf(-x));
}
// "critical": f32-step sigmoid with near-correctly-rounded expf via f64.
__device__ __forceinline__ float sig_crit(float x) {
#pragma clang fp contract(off)
  double e = exp(-(double)x);
  float ef = (float)e;
  return 1.0f / (1.0f + ef);
}

// ---- KA: zero hist/counters + precompute cheap sigmoid(obj) ----
__global__ __launch_bounds__(256) void kA(const float* __restrict__ o0,
                                          const float* __restrict__ o1,
                                          const float* __restrict__ o2,
                                          u32* __restrict__ hist,
                                          u32* __restrict__ cnt,
                                          float* __restrict__ sobj) {
  int t = blockIdx.x * 256 + threadIdx.x;
  if (t < 3 * 2048) hist[t] = 0u;
  if (t < 8) cnt[t] = 0u;
  if (t < 100800) {
    const float* o; int a;
    if (t < 76800)      { o = o0; a = t; }
    else if (t < 96000) { o = o1; a = t - 76800; }
    else                { o = o2; a = t - 96000; }
    sobj[t] = sig_fast(o[a]);
  }
}

// block -> (level, elem base). E0=6000*1024, E1=1500*1024, E2=375*1024 (exact).
__device__ __forceinline__ void block_map(int bid, int& l, int& e0, int& sob) {
  if (bid < 6000)      { l = 0; e0 = bid * 1024;          sob = 0; }
  else if (bid < 7500) { l = 1; e0 = (bid - 6000) * 1024; sob = 76800; }
  else                 { l = 2; e0 = (bid - 7500) * 1024; sob = 96000; }
}

// ---- KB: histogram of cheap product bits (bin = bits>>19, 2048 bins) ----
__global__ __launch_bounds__(256) void kB(const float* __restrict__ c0,
                                          const float* __restrict__ c1,
                                          const float* __restrict__ c2,
                                          const float* __restrict__ sobj,
                                          u32* __restrict__ ghist) {
  __shared__ u32 lh[2048];
  for (int i = threadIdx.x; i < 2048; i += 256) lh[i] = 0u;
  __syncthreads();
  int l, e0, sob; block_map(blockIdx.x, l, e0, sob);
  const float* cls = (l == 0) ? c0 : (l == 1) ? c1 : c2;
  int e = e0 + threadIdx.x * 4;
  float4 cv = *(const float4*)(cls + e);
  float so = sobj[sob + e / 80];
  float cc[4] = {cv.x, cv.y, cv.z, cv.w};
#pragma unroll
  for (int k = 0; k < 4; k++) {
    float p = so * sig_fast(cc[k]);
    atomicAdd(&lh[__float_as_uint(p) >> 19], 1u);
  }
  __syncthreads();
  for (int i = threadIdx.x; i < 2048; i += 256) {
    u32 v = lh[i];
    if (v) atomicAdd(&ghist[l * 2048 + i], v);
  }
}

// ---- K2: pick per-level threshold bin (cum from top >= TARGET) ----
__global__ void k2(const u32* __restrict__ ghist, u32* __restrict__ cnt) {
  int l = threadIdx.x;
  if (l < 3) {
    u32 c = 0; int b = 2047;
    for (; b >= 0; --b) { c += ghist[l * 2048 + b]; if (c >= TARGET) break; }
    if (b < 0) b = 0;
    cnt[4 + l] = ((u32)b) << 19;
  }
}

// ---- K3: compact candidates with exact score bits >= T ----
__global__ __launch_bounds__(256) void k3(const float* __restrict__ c0,
                                          const float* __restrict__ c1,
                                          const float* __restrict__ c2,
                                          const float* __restrict__ o0,
                                          const float* __restrict__ o1,
                                          const float* __restrict__ o2,
                                          const float* __restrict__ sobj,
                                          u32* __restrict__ cnt,
                                          u64* __restrict__ cand) {
  int l, e0, sob; block_map(blockIdx.x, l, e0, sob);
  const float* cls = (l == 0) ? c0 : (l == 1) ? c1 : c2;
  const float* obj = (l == 0) ? o0 : (l == 1) ? o1 : o2;
  u32 T = cnt[4 + l];
  u32 Tm = (T > 64u) ? (T - 64u) : 0u;
  int e = e0 + threadIdx.x * 4;
  float4 cv = *(const float4*)(cls + e);
  int a = e / 80;
  float so = sobj[sob + a];
  float cc[4] = {cv.x, cv.y, cv.z, cv.w};
#pragma unroll
  for (int k = 0; k < 4; k++) {
    float pch = so * sig_fast(cc[k]);
    if (__float_as_uint(pch) >= Tm) {
      // exact recompute in reference-matching precision
      float soe = sig_crit(obj[a]);
      float sce = sig_crit(cc[k]);
      float p = soe * sce;
      u32 bits = __float_as_uint(p);
      if (bits >= T) {
        u32 slot = atomicAdd(&cnt[l], 1u);
        if (slot < CAP) {
          float s = __fsqrt_rn(p);
          u64 key = ((u64)__float_as_uint(s) << 32) | (u32)(~((u32)(e + k)));
          cand[(size_t)l * CAP + slot] = key;
        }
      }
    }
  }
}

// ---- bitonic (descending) in LDS ----
template <int BLK>
__device__ void bitonic_desc(u64* S, u32 sz) {
  for (u32 k = 2; k <= sz; k <<= 1) {
    for (u32 j = k >> 1; j > 0; j >>= 1) {
      for (u32 i = threadIdx.x; i < sz; i += BLK) {
        u32 ixj = i ^ j;
        if (ixj > i) {
          u64 a = S[i], b = S[ixj];
          bool up = ((i & k) == 0);
          if ((a < b) == up) { S[i] = b; S[ixj] = a; }
        }
      }
      __syncthreads();
    }
  }
}

// ---- K4: per-level sort, keep top-1000 ----
__global__ __launch_bounds__(256) void k4(const u64* __restrict__ cand,
                                          const u32* __restrict__ cnt,
                                          u32* __restrict__ gsbits,
                                          u32* __restrict__ gflat) {
  __shared__ u64 S[CAP];
  int l = blockIdx.x;
  u32 n = cnt[l]; if (n > CAP) n = CAP;
  u32 sz = 1024; while (sz < n) sz <<= 1;
  for (u32 i = threadIdx.x; i < sz; i += 256)
    S[i] = (i < n) ? cand[(size_t)l * CAP + i] : 0ull;
  __syncthreads();
  bitonic_desc<256>(S, sz);
  for (u32 r = threadIdx.x; r < KLVL; r += 256) {
    u64 key = (r < n) ? S[r] : 0ull;
    gsbits[l * KLVL + r] = (u32)(key >> 32);
    gflat [l * KLVL + r] = (r < n) ? ~((u32)key) : 0u;
  }
}

// ---- K5: global sort of 3000 (stable by concat position) ----
__global__ __launch_bounds__(256) void k5(const u32* __restrict__ gsbits,
                                          u32* __restrict__ srt) {
  __shared__ u64 S[4096];
  for (u32 i = threadIdx.x; i < 4096; i += 256)
    S[i] = (i < 3000) ? (((u64)gsbits[i] << 32) | (u32)(~i)) : 0ull;
  __syncthreads();
  bitonic_desc<256>(S, 4096);
  for (u32 r = threadIdx.x; r < 3000; r += 256)
    srt[r] = ~((u32)S[r]);
}

// ---- K6: decode boxes, build NMS (offset-quantized) coords ----
__global__ __launch_bounds__(256) void k6(const float* __restrict__ r0,
                                          const float* __restrict__ r1,
                                          const float* __restrict__ r2,
                                          const u32* __restrict__ srt,
                                          const u32* __restrict__ gsbits,
                                          const u32* __restrict__ gflat,
                                          float* __restrict__ qx1, float* __restrict__ qy1,
                                          float* __restrict__ qx2, float* __restrict__ qy2,
                                          float* __restrict__ area,
                                          float* __restrict__ score,
                                          u32* __restrict__ label,
                                          u32* __restrict__ valid,
                                          u32* __restrict__ keep,
                                          float* __restrict__ obox) {
#pragma clang fp contract(off)
  int r = blockIdx.x * 256 + threadIdx.x;
  if (r >= 3000) return;
  u32 gpos = srt[r];
  int l = (int)(gpos / 1000u);
  u32 flat = gflat[gpos];
  float sc = __uint_as_float(gsbits[gpos]);
  int a = (int)(flat / NCLS), c = (int)(flat % NCLS);
  int cell = a / 3, bi = a % 3;
  int f = (l == 0) ? 160 : (l == 1) ? 80 : 40;
  float stride = (float)(8 << l);
  float gx = (float)(cell % f), gy = (float)(cell / f);
  const float* rp = ((l == 0) ? r0 : (l == 1) ? r1 : r2) + (size_t)a * 4;
  float t0 = rp[0], t1 = rp[1], t2 = rp[2], t3 = rp[3];
  float sx = 1.0f / (1.0f + expf(-t0));
  float sy = 1.0f / (1.0f + expf(-t1));
  float w = expf(t2) * cANCH[l][bi][0];
  float h = expf(t3) * cANCH[l][bi][1];
  float cx = (sx + gx) * stride;
  float cy = (sy + gy) * stride;
  float hw = w * 0.5f, hh = h * 0.5f;
  float x1 = cx - hw, y1 = cy - hh, x2 = cx + hw, y2 = cy + hh;
  obox[r * 4 + 0] = x1; obox[r * 4 + 1] = y1;
  obox[r * 4 + 2] = x2; obox[r * 4 + 3] = y2;
  // reference NMS treats [x1,y1,x2,y2] as [cx,cy,w,h]
  float hx2 = x2 * 0.5f, hy2 = y2 * 0.5f;
  float bx1 = x1 - hx2, by1 = y1 - hy2, bx2 = x1 + hx2, by2 = y1 + hy2;
  float off = (float)c * 1e7f;              // f32 quantization is load-bearing
  float a1 = bx1 + off, a2 = bx2 + off;
  qx1[r] = a1; qy1[r] = by1; qx2[r] = a2; qy2[r] = by2;
  area[r] = (a2 - a1) * (by2 - by1);
  score[r] = sc; label[r] = (u32)c;
  valid[r] = (sc > 0.3f) ? 1u : 0u;
  keep[r] = 0u;
}

// ---- K7: per-class greedy NMS (cross-class IoU <= ~4e-6 < 0.5 due to offsets) ----
#define CAPC 1024
__global__ __launch_bounds__(64) void k7(const float* __restrict__ qx1,
                                         const float* __restrict__ qy1,
                                         const float* __restrict__ qx2,
                                         const float* __restrict__ qy2,
                                         const float* __restrict__ area,
                                         const u32* __restrict__ label,
                                         const u32* __restrict__ valid,
                                         u32* __restrict__ keep) {
#pragma clang fp contract(off)
  __shared__ u32 LIST[CAPC];
  __shared__ float X1[CAPC], Y1[CAPC], X2[CAPC], Y2[CAPC], AR[CAPC];
  __shared__ u32 KP[CAPC];
  u32 c = blockIdx.x;
  int lane = threadIdx.x;
  u32 n = 0;
  for (int base = 0; base < 3000; base += 64) {
    int j = base + lane;
    bool m = false;
    if (j < 3000) m = (label[j] == c) && (valid[j] != 0u);
    u64 mask = __ballot(m ? 1 : 0);
    u32 pos = n + (u32)__popcll(mask & ((1ull << lane) - 1ull));
    if (m && pos < CAPC) {
      LIST[pos] = (u32)j;
      X1[pos] = qx1[j]; Y1[pos] = qy1[j];
      X2[pos] = qx2[j]; Y2[pos] = qy2[j];
      AR[pos] = area[j]; KP[pos] = 1u;
    }
    n += (u32)__popcll(mask);
  }
  if (n > CAPC) n = CAPC;
  __syncthreads();
  for (u32 i = 0; i < n; ++i) {
    if (KP[i]) {
      float xi1 = X1[i], yi1 = Y1[i], xi2 = X2[i], yi2 = Y2[i], ai = AR[i];
      for (u32 j = i + 1 + (u32)lane; j < n; j += 64) {
        if (KP[j]) {
          float xx1 = fmaxf(xi1, X1[j]);
          float yy1 = fmaxf(yi1, Y1[j]);
          float xx2 = fminf(xi2, X2[j]);
          float yy2 = fminf(yi2, Y2[j]);
          float iw = xx2 - xx1, ih = yy2 - yy1;
          float inter = fmaxf(1e-10f, iw) * fmaxf(1e-10f, ih);
          float den = ai + AR[j] - inter + 1e-14f;
          if (inter / den > 0.5f) KP[j] = 0u;
        }
      }
    }
    __syncthreads();
  }
  for (u32 j = (u32)lane; j < n; j += 64) keep[LIST[j]] = KP[j];
}

// ---- K8: masked outputs (all f32): boxes | scores | labels | keep ----
__global__ __launch_bounds__(256) void k8(const float* __restrict__ obox,
                                          const float* __restrict__ score,
                                          const u32* __restrict__ label,
                                          const u32* __restrict__ keep,
                                          float* __restrict__ out) {
  int r = blockIdx.x * 256 + threadIdx.x;
  if (r >= 3000) return;
  bool k = keep[r] != 0u;
  float4 b;
  if (k) b = *(const float4*)(obox + (size_t)r * 4);
  else   b = make_float4(0.f, 0.f, 0.f, 0.f);
  ((float4*)out)[r] = b;
  out[12000 + r] = k ? score[r] : 0.0f;
  out[15000 + r] = k ? (float)(int)label[r] : -1.0f;
  out[18000 + r] = k ? 1.0f : 0.0f;
}

extern "C" void kernel_launch(void* const* d_in, const int* in_sizes, int n_in,
                              void* d_out, int out_size, void* d_ws, size_t ws_size,
                              hipStream_t stream) {
  const float* obj0 = (const float*)d_in[0];
  const float* cls0 = (const float*)d_in[1];
  const float* reg0 = (const float*)d_in[2];
  const float* obj1 = (const float*)d_in[3];
  const float* cls1 = (const float*)d_in[4];
  const float* reg1 = (const float*)d_in[5];
  const float* obj2 = (const float*)d_in[6];
  const float* cls2 = (const float*)d_in[7];
  const float* reg2 = (const float*)d_in[8];
  char* ws = (char*)d_ws;
  u64* cand   = (u64*)(ws + OFF_CAND);
  u32* hist   = (u32*)(ws + OFF_HIST);
  u32* cnt    = (u32*)(ws + OFF_CNT);
  u32* gflat  = (u32*)(ws + OFF_GFLAT);
  u32* gsbits = (u32*)(ws + OFF_GSB);
  u32* srt    = (u32*)(ws + OFF_SRT);
  float* qx1  = (float*)(ws + OFF_QX1);
  float* qy1  = (float*)(ws + OFF_QY1);
  float* qx2  = (float*)(ws + OFF_QX2);
  float* qy2  = (float*)(ws + OFF_QY2);
  float* area = (float*)(ws + OFF_AREA);
  float* score= (float*)(ws + OFF_SCORE);
  u32* label  = (u32*)(ws + OFF_LABEL);
  u32* valid  = (u32*)(ws + OFF_VALID);
  u32* keep   = (u32*)(ws + OFF_KEEP);
  float* obox = (float*)(ws + OFF_OBOX);
  float* sobj = (float*)(ws + OFF_SOBJ);
  float* out  = (float*)d_out;

  kA<<<394, 256, 0, stream>>>(obj0, obj1, obj2, hist, cnt, sobj);
  kB<<<7875, 256, 0, stream>>>(cls0, cls1, cls2, sobj, hist);
  k2<<<1, 64, 0, stream>>>(hist, cnt);
  k3<<<7875, 256, 0, stream>>>(cls0, cls1, cls2, obj0, obj1, obj2, sobj, cnt, cand);
  k4<<<3, 256, 0, stream>>>(cand, cnt, gsbits, gflat);
  k5<<<1, 256, 0, stream>>>(gsbits, srt);
  k6<<<12, 256, 0, stream>>>(reg0, reg1, reg2, srt, gsbits, gflat,
                             qx1, qy1, qx2, qy2, area, score, label, valid, keep, obox);
  k7<<<80, 64, 0, stream>>>(qx1, qy1, qx2, qy2, area, label, valid, keep);
  k8<<<12, 256, 0, stream>>>(obox, score, label, keep, out);
}

// Round 2
// 409.184 us; speedup vs baseline: 1.3906x; 1.3906x over previous
//
#include <hip/hip_runtime.h>
#include <hip/hip_bf16.h>
#include <math.h>

typedef unsigned int u32;
typedef unsigned long long u64;

#define NCLS 80
#define KLVL 1000
#define CAP  8192
#define TARGET 1100u

// workspace byte offsets (all 16B aligned)
#define OFF_CAND   0u        // u64 [3][8192]
#define OFF_HIST   196608u   // u32 [3][2048]
#define OFF_CNT    221184u   // u32 [8]: [0..2]=cand counts, [4..6]=threshold bits
#define OFF_GFLAT  221216u   // u32 [3000]
#define OFF_GSB    233216u   // u32 [3000]
#define OFF_SRT    245216u   // u32 [3000]
#define OFF_QX1    257216u   // f32 [3000]
#define OFF_QY1    269216u
#define OFF_QX2    281216u
#define OFF_QY2    293216u
#define OFF_AREA   305216u
#define OFF_SCORE  317216u
#define OFF_LABEL  329216u   // u32
#define OFF_VALID  341216u   // u32
#define OFF_KEEP   353216u   // u32
#define OFF_OBOX   365216u   // f32 [3000][4]
#define OFF_SOBJ   413216u   // f32 [100800] cheap sigmoid(obj)

__constant__ float cANCH[3][3][2] = {
  {{10.f,13.f},{16.f,30.f},{33.f,23.f}},
  {{30.f,61.f},{62.f,45.f},{59.f,119.f}},
  {{116.f,90.f},{156.f,198.f},{373.f,326.f}}
};

// ---- sigmoid helpers ----
__device__ __forceinline__ float sig_fast(float x) {
  return 1.0f / (1.0f + __expf(-x));
}
// "critical": f32-step sigmoid with near-correctly-rounded expf via f64.
__device__ __forceinline__ float sig_crit(float x) {
#pragma clang fp contract(off)
  double e = exp(-(double)x);
  float ef = (float)e;
  return 1.0f / (1.0f + ef);
}

// ---- KA: zero hist/counters/outputs + precompute cheap sigmoid(obj) ----
__global__ __launch_bounds__(256) void kA(const float* __restrict__ o0,
                                          const float* __restrict__ o1,
                                          const float* __restrict__ o2,
                                          u32* __restrict__ hist,
                                          u32* __restrict__ cnt,
                                          u32* __restrict__ gsbits,
                                          u32* __restrict__ gflat,
                                          float* __restrict__ sobj) {
  int t = blockIdx.x * 256 + threadIdx.x;
  if (t < 3 * 2048) hist[t] = 0u;
  if (t < 8) cnt[t] = 0u;
  if (t < 3000) { gsbits[t] = 0u; gflat[t] = 0u; }
  if (t < 100800) {
    const float* o; int a;
    if (t < 76800)      { o = o0; a = t; }
    else if (t < 96000) { o = o1; a = t - 76800; }
    else                { o = o2; a = t - 96000; }
    sobj[t] = sig_fast(o[a]);
  }
}

// block -> (level, elem base). E0=6000*1024, E1=1500*1024, E2=375*1024 (exact).
__device__ __forceinline__ void block_map(int bid, int& l, int& e0, int& sob) {
  if (bid < 6000)      { l = 0; e0 = bid * 1024;          sob = 0; }
  else if (bid < 7500) { l = 1; e0 = (bid - 6000) * 1024; sob = 76800; }
  else                 { l = 2; e0 = (bid - 7500) * 1024; sob = 96000; }
}

// ---- KB: histogram of cheap product bits (bin = bits>>19, 2048 bins) ----
__global__ __launch_bounds__(256) void kB(const float* __restrict__ c0,
                                          const float* __restrict__ c1,
                                          const float* __restrict__ c2,
                                          const float* __restrict__ sobj,
                                          u32* __restrict__ ghist) {
  __shared__ u32 lh[2048];
  for (int i = threadIdx.x; i < 2048; i += 256) lh[i] = 0u;
  __syncthreads();
  int l, e0, sob; block_map(blockIdx.x, l, e0, sob);
  const float* cls = (l == 0) ? c0 : (l == 1) ? c1 : c2;
  int e = e0 + threadIdx.x * 4;
  float4 cv = *(const float4*)(cls + e);
  float so = sobj[sob + e / 80];
  float cc[4] = {cv.x, cv.y, cv.z, cv.w};
#pragma unroll
  for (int k = 0; k < 4; k++) {
    float p = so * sig_fast(cc[k]);
    atomicAdd(&lh[__float_as_uint(p) >> 19], 1u);
  }
  __syncthreads();
  for (int i = threadIdx.x; i < 2048; i += 256) {
    u32 v = lh[i];
    if (v) atomicAdd(&ghist[l * 2048 + i], v);
  }
}

// ---- K2: pick per-level threshold bin (cum from top >= TARGET) ----
__global__ void k2(const u32* __restrict__ ghist, u32* __restrict__ cnt) {
  int l = threadIdx.x;
  if (l < 3) {
    u32 c = 0; int b = 2047;
    for (; b >= 0; --b) { c += ghist[l * 2048 + b]; if (c >= TARGET) break; }
    if (b < 0) b = 0;
    cnt[4 + l] = ((u32)b) << 19;
  }
}

// ---- K3: compact candidates with exact score bits >= T ----
__global__ __launch_bounds__(256) void k3(const float* __restrict__ c0,
                                          const float* __restrict__ c1,
                                          const float* __restrict__ c2,
                                          const float* __restrict__ o0,
                                          const float* __restrict__ o1,
                                          const float* __restrict__ o2,
                                          const float* __restrict__ sobj,
                                          u32* __restrict__ cnt,
                                          u64* __restrict__ cand) {
  int l, e0, sob; block_map(blockIdx.x, l, e0, sob);
  const float* cls = (l == 0) ? c0 : (l == 1) ? c1 : c2;
  const float* obj = (l == 0) ? o0 : (l == 1) ? o1 : o2;
  u32 T = cnt[4 + l];
  u32 Tm = (T > 64u) ? (T - 64u) : 0u;
  int e = e0 + threadIdx.x * 4;
  float4 cv = *(const float4*)(cls + e);
  int a = e / 80;
  float so = sobj[sob + a];
  float cc[4] = {cv.x, cv.y, cv.z, cv.w};
#pragma unroll
  for (int k = 0; k < 4; k++) {
    float pch = so * sig_fast(cc[k]);
    if (__float_as_uint(pch) >= Tm) {
      // exact recompute in reference-matching precision
      float soe = sig_crit(obj[a]);
      float sce = sig_crit(cc[k]);
      float p = soe * sce;
      u32 bits = __float_as_uint(p);
      if (bits >= T) {
        u32 slot = atomicAdd(&cnt[l], 1u);
        if (slot < CAP) {
          float s = __fsqrt_rn(p);
          u64 key = ((u64)__float_as_uint(s) << 32) | (u32)(~((u32)(e + k)));
          cand[(size_t)l * CAP + slot] = key;
        }
      }
    }
  }
}

// ---- R1: per-level rank-by-counting, scatter top-1000 in sorted order ----
// rank = #{keys > mine}; keys unique (flat idx embedded) => exact stable order.
__global__ __launch_bounds__(256) void r1(const u64* __restrict__ cand,
                                          const u32* __restrict__ cnt,
                                          u32* __restrict__ gsbits,
                                          u32* __restrict__ gflat) {
  int l = blockIdx.x >> 5;        // 32 blocks per level
  int b = blockIdx.x & 31;
  u32 n = cnt[l]; if (n > CAP) n = CAP;
  if ((u32)(b * 256) >= n) return;        // whole-block uniform exit
  const u64* base = cand + (size_t)l * CAP;
  __shared__ u64 S[1024];
  u32 idx = (u32)(b * 256 + threadIdx.x);
  u64 mykey = (idx < n) ? base[idx] : 0ull;
  u32 rank = 0;
  for (u32 c0 = 0; c0 < n; c0 += 1024) {
    u32 m = (n - c0 < 1024u) ? (n - c0) : 1024u;
    __syncthreads();
    for (u32 i = threadIdx.x; i < 1024; i += 256)
      S[i] = (c0 + i < n) ? base[c0 + i] : 0ull;
    __syncthreads();
    if (idx < n) {
#pragma unroll 4
      for (u32 i = 0; i < m; ++i) rank += (S[i] > mykey) ? 1u : 0u;
    }
  }
  if (idx < n && rank < KLVL) {
    gsbits[l * KLVL + rank] = (u32)(mykey >> 32);
    gflat [l * KLVL + rank] = ~((u32)mykey);
  }
}

// ---- R2: global rank of 3000 (stable by concat position), scatter order ----
__global__ __launch_bounds__(256) void r2(const u32* __restrict__ gsbits,
                                          u32* __restrict__ srt) {
  __shared__ u64 S[3000];
  int t = blockIdx.x * 256 + threadIdx.x;  // 12 blocks
  for (u32 i = threadIdx.x; i < 3000; i += 256)
    S[i] = (((u64)gsbits[i]) << 32) | (u32)(~i);
  __syncthreads();
  if (t < 3000) {
    u64 my = (((u64)gsbits[t]) << 32) | (u32)(~t);
    u32 rank = 0;
#pragma unroll 4
    for (u32 i = 0; i < 3000; ++i) rank += (S[i] > my) ? 1u : 0u;
    srt[rank] = (u32)t;
  }
}

// ---- K6: decode boxes, build NMS (offset-quantized) coords ----
__global__ __launch_bounds__(256) void k6(const float* __restrict__ r0,
                                          const float* __restrict__ r1_,
                                          const float* __restrict__ r2_,
                                          const u32* __restrict__ srt,
                                          const u32* __restrict__ gsbits,
                                          const u32* __restrict__ gflat,
                                          float* __restrict__ qx1, float* __restrict__ qy1,
                                          float* __restrict__ qx2, float* __restrict__ qy2,
                                          float* __restrict__ area,
                                          float* __restrict__ score,
                                          u32* __restrict__ label,
                                          u32* __restrict__ valid,
                                          u32* __restrict__ keep,
                                          float* __restrict__ obox) {
#pragma clang fp contract(off)
  int r = blockIdx.x * 256 + threadIdx.x;
  if (r >= 3000) return;
  u32 gpos = srt[r];
  int l = (int)(gpos / 1000u);
  u32 flat = gflat[gpos];
  float sc = __uint_as_float(gsbits[gpos]);
  int a = (int)(flat / NCLS), c = (int)(flat % NCLS);
  int cell = a / 3, bi = a % 3;
  int f = (l == 0) ? 160 : (l == 1) ? 80 : 40;
  float stride = (float)(8 << l);
  float gx = (float)(cell % f), gy = (float)(cell / f);
  const float* rp = ((l == 0) ? r0 : (l == 1) ? r1_ : r2_) + (size_t)a * 4;
  float t0 = rp[0], t1 = rp[1], t2 = rp[2], t3 = rp[3];
  float sx = 1.0f / (1.0f + expf(-t0));
  float sy = 1.0f / (1.0f + expf(-t1));
  float w = expf(t2) * cANCH[l][bi][0];
  float h = expf(t3) * cANCH[l][bi][1];
  float cx = (sx + gx) * stride;
  float cy = (sy + gy) * stride;
  float hw = w * 0.5f, hh = h * 0.5f;
  float x1 = cx - hw, y1 = cy - hh, x2 = cx + hw, y2 = cy + hh;
  obox[r * 4 + 0] = x1; obox[r * 4 + 1] = y1;
  obox[r * 4 + 2] = x2; obox[r * 4 + 3] = y2;
  // reference NMS treats [x1,y1,x2,y2] as [cx,cy,w,h]
  float hx2 = x2 * 0.5f, hy2 = y2 * 0.5f;
  float bx1 = x1 - hx2, by1 = y1 - hy2, bx2 = x1 + hx2, by2 = y1 + hy2;
  float off = (float)c * 1e7f;              // f32 quantization is load-bearing
  float a1 = bx1 + off, a2 = bx2 + off;
  qx1[r] = a1; qy1[r] = by1; qx2[r] = a2; qy2[r] = by2;
  area[r] = (a2 - a1) * (by2 - by1);
  score[r] = sc; label[r] = (u32)c;
  valid[r] = (sc > 0.3f) ? 1u : 0u;
  keep[r] = 0u;
}

// ---- K7: per-class greedy NMS (cross-class IoU <= ~4e-6 < 0.5 due to offsets) ----
#define CAPC 1024
__global__ __launch_bounds__(64) void k7(const float* __restrict__ qx1,
                                         const float* __restrict__ qy1,
                                         const float* __restrict__ qx2,
                                         const float* __restrict__ qy2,
                                         const float* __restrict__ area,
                                         const u32* __restrict__ label,
                                         const u32* __restrict__ valid,
                                         u32* __restrict__ keep) {
#pragma clang fp contract(off)
  __shared__ u32 LIST[CAPC];
  __shared__ float X1[CAPC], Y1[CAPC], X2[CAPC], Y2[CAPC], AR[CAPC];
  __shared__ u32 KP[CAPC];
  u32 c = blockIdx.x;
  int lane = threadIdx.x;
  u32 n = 0;
  for (int base = 0; base < 3000; base += 64) {
    int j = base + lane;
    bool m = false;
    if (j < 3000) m = (label[j] == c) && (valid[j] != 0u);
    u64 mask = __ballot(m ? 1 : 0);
    u32 pos = n + (u32)__popcll(mask & ((1ull << lane) - 1ull));
    if (m && pos < CAPC) {
      LIST[pos] = (u32)j;
      X1[pos] = qx1[j]; Y1[pos] = qy1[j];
      X2[pos] = qx2[j]; Y2[pos] = qy2[j];
      AR[pos] = area[j]; KP[pos] = 1u;
    }
    n += (u32)__popcll(mask);
  }
  if (n > CAPC) n = CAPC;
  __syncthreads();
  for (u32 i = 0; i < n; ++i) {
    if (KP[i]) {
      float xi1 = X1[i], yi1 = Y1[i], xi2 = X2[i], yi2 = Y2[i], ai = AR[i];
      for (u32 j = i + 1 + (u32)lane; j < n; j += 64) {
        if (KP[j]) {
          float xx1 = fmaxf(xi1, X1[j]);
          float yy1 = fmaxf(yi1, Y1[j]);
          float xx2 = fminf(xi2, X2[j]);
          float yy2 = fminf(yi2, Y2[j]);
          float iw = xx2 - xx1, ih = yy2 - yy1;
          float inter = fmaxf(1e-10f, iw) * fmaxf(1e-10f, ih);
          float den = ai + AR[j] - inter + 1e-14f;
          if (inter / den > 0.5f) KP[j] = 0u;
        }
      }
    }
    __syncthreads();
  }
  for (u32 j = (u32)lane; j < n; j += 64) keep[LIST[j]] = KP[j];
}

// ---- K8: masked outputs (all f32): boxes | scores | labels | keep ----
__global__ __launch_bounds__(256) void k8(const float* __restrict__ obox,
                                          const float* __restrict__ score,
                                          const u32* __restrict__ label,
                                          const u32* __restrict__ keep,
                                          float* __restrict__ out) {
  int r = blockIdx.x * 256 + threadIdx.x;
  if (r >= 3000) return;
  bool k = keep[r] != 0u;
  float4 b;
  if (k) b = *(const float4*)(obox + (size_t)r * 4);
  else   b = make_float4(0.f, 0.f, 0.f, 0.f);
  ((float4*)out)[r] = b;
  out[12000 + r] = k ? score[r] : 0.0f;
  out[15000 + r] = k ? (float)(int)label[r] : -1.0f;
  out[18000 + r] = k ? 1.0f : 0.0f;
}

extern "C" void kernel_launch(void* const* d_in, const int* in_sizes, int n_in,
                              void* d_out, int out_size, void* d_ws, size_t ws_size,
                              hipStream_t stream) {
  const float* obj0 = (const float*)d_in[0];
  const float* cls0 = (const float*)d_in[1];
  const float* reg0 = (const float*)d_in[2];
  const float* obj1 = (const float*)d_in[3];
  const float* cls1 = (const float*)d_in[4];
  const float* reg1 = (const float*)d_in[5];
  const float* obj2 = (const float*)d_in[6];
  const float* cls2 = (const float*)d_in[7];
  const float* reg2 = (const float*)d_in[8];
  char* ws = (char*)d_ws;
  u64* cand   = (u64*)(ws + OFF_CAND);
  u32* hist   = (u32*)(ws + OFF_HIST);
  u32* cnt    = (u32*)(ws + OFF_CNT);
  u32* gflat  = (u32*)(ws + OFF_GFLAT);
  u32* gsbits = (u32*)(ws + OFF_GSB);
  u32* srt    = (u32*)(ws + OFF_SRT);
  float* qx1  = (float*)(ws + OFF_QX1);
  float* qy1  = (float*)(ws + OFF_QY1);
  float* qx2  = (float*)(ws + OFF_QX2);
  float* qy2  = (float*)(ws + OFF_QY2);
  float* area = (float*)(ws + OFF_AREA);
  float* score= (float*)(ws + OFF_SCORE);
  u32* label  = (u32*)(ws + OFF_LABEL);
  u32* valid  = (u32*)(ws + OFF_VALID);
  u32* keep   = (u32*)(ws + OFF_KEEP);
  float* obox = (float*)(ws + OFF_OBOX);
  float* sobj = (float*)(ws + OFF_SOBJ);
  float* out  = (float*)d_out;

  kA<<<394, 256, 0, stream>>>(obj0, obj1, obj2, hist, cnt, gsbits, gflat, sobj);
  kB<<<7875, 256, 0, stream>>>(cls0, cls1, cls2, sobj, hist);
  k2<<<1, 64, 0, stream>>>(hist, cnt);
  k3<<<7875, 256, 0, stream>>>(cls0, cls1, cls2, obj0, obj1, obj2, sobj, cnt, cand);
  r1<<<96, 256, 0, stream>>>(cand, cnt, gsbits, gflat);
  r2<<<12, 256, 0, stream>>>(gsbits, srt);
  k6<<<12, 256, 0, stream>>>(reg0, reg1, reg2, srt, gsbits, gflat,
                             qx1, qy1, qx2, qy2, area, score, label, valid, keep, obox);
  k7<<<80, 64, 0, stream>>>(qx1, qy1, qx2, qy2, area, label, valid, keep);
  k8<<<12, 256, 0, stream>>>(obox, score, label, keep, out);
}